// Round 18
// baseline (686.557 us; speedup 1.0000x reference)
//
#include <hip/hip_runtime.h>
#include <math.h>

#define NB 8
#define NPTS 4096
#define NCH 64
#define NOUT 64
#define KNN 16
#define HALFC 2048

#define GLOBAL_AS const __attribute__((address_space(1)))
#define LDS_AS __attribute__((address_space(3)))

// ws layout in floats:
#define WS_SQ  0
#define WS_PT  (NB*NPTS)                        // 32768
#define WS_QT  (WS_PT + NB*NPTS*64)             // + 2097152
#define WS_VH  (WS_QT + NB*NPTS*64)             // fp32, NB*NPTS*32
#define WS_IH  (WS_VH + NB*NPTS*32)             // uint16, NB*NPTS*32 (2MB)

// ----------------------------- K1: P/Q precompute (+ fused sq) -------------
__global__ __launch_bounds__(256) void k_pq(const float* __restrict__ fea,
                                            const float* __restrict__ Wf1,
                                            const float* __restrict__ bf1,
                                            float* __restrict__ Pt,
                                            float* __restrict__ Qt,
                                            float* __restrict__ sq) {
    __shared__ __align__(16) float feaT[64][64];    // [c][n]
    __shared__ __align__(16) float WT[64][132];     // [c][o'], o' in 0..127
    __shared__ float sb[64];

    const int b = blockIdx.y;
    const int n0 = blockIdx.x * 64;
    const int tid = threadIdx.x;
    const int to = tid & 15, tn = tid >> 4;
    const float* feab = fea + (size_t)b * NCH * NPTS;

#pragma unroll
    for (int i = 0; i < 4; ++i) {
        int e = i * 1024 + tid * 4;
        int c = e >> 6, nn = e & 63;
        *(float4*)&feaT[c][nn] = *(const float4*)&feab[c * NPTS + n0 + nn];
    }
#pragma unroll
    for (int i = 0; i < 8; ++i) {
        int g = tid * 32 + i * 4;
        int op = g >> 6, c = g & 63;
        const float* src = (op < 64) ? &Wf1[op * 128 + c]
                                     : &Wf1[(op - 64) * 128 + 64 + c];
        float4 w = *(const float4*)src;
        WT[c + 0][op] = w.x; WT[c + 1][op] = w.y;
        WT[c + 2][op] = w.z; WT[c + 3][op] = w.w;
    }
    if (tid < 64) sb[tid] = bf1[tid];
    __syncthreads();

    if (tid < 64) {                                 // fused k_sq
        float s = 0.f;
#pragma unroll
        for (int c = 0; c < 64; ++c) {
            float v = feaT[c][tid];
            s = fmaf(v, v, s);
        }
        sq[b * NPTS + n0 + tid] = s;
    }

    float acc[4][8];
#pragma unroll
    for (int ni = 0; ni < 4; ++ni)
#pragma unroll
        for (int oj = 0; oj < 8; ++oj) acc[ni][oj] = 0.f;

#pragma unroll 4
    for (int c = 0; c < 64; ++c) {
        float4 a  = *(const float4*)&feaT[c][tn * 4];
        float4 w0 = *(const float4*)&WT[c][to * 8];
        float4 w1 = *(const float4*)&WT[c][to * 8 + 4];
        float av[4] = {a.x, a.y, a.z, a.w};
        float wv[8] = {w0.x, w0.y, w0.z, w0.w, w1.x, w1.y, w1.z, w1.w};
#pragma unroll
        for (int ni = 0; ni < 4; ++ni)
#pragma unroll
            for (int oj = 0; oj < 8; ++oj)
                acc[ni][oj] = fmaf(av[ni], wv[oj], acc[ni][oj]);
    }

    const int opb = to * 8;
#pragma unroll
    for (int ni = 0; ni < 4; ++ni) {
        int n = n0 + tn * 4 + ni;
        size_t base = ((size_t)b * NPTS + n) * 64;
        if (opb < 64) {     // P half: add bias
            float4 o0, o1;
            o0.x = acc[ni][0] + sb[opb + 0]; o0.y = acc[ni][1] + sb[opb + 1];
            o0.z = acc[ni][2] + sb[opb + 2]; o0.w = acc[ni][3] + sb[opb + 3];
            o1.x = acc[ni][4] + sb[opb + 4]; o1.y = acc[ni][5] + sb[opb + 5];
            o1.z = acc[ni][6] + sb[opb + 6]; o1.w = acc[ni][7] + sb[opb + 7];
            *(float4*)&Pt[base + opb]     = o0;
            *(float4*)&Pt[base + opb + 4] = o1;
        } else {            // Q half: no bias
            float4 o0, o1;
            o0.x = acc[ni][0]; o0.y = acc[ni][1]; o0.z = acc[ni][2]; o0.w = acc[ni][3];
            o1.x = acc[ni][4]; o1.y = acc[ni][5]; o1.z = acc[ni][6]; o1.w = acc[ni][7];
            *(float4*)&Qt[base + opb - 64]     = o0;
            *(float4*)&Qt[base + opb - 64 + 4] = o1;
        }
    }
}

// ------------------------------------------------------- K2: fused KNN ------
// r18: r12 micro-structure (32-row panels, acc[2][4], ballot+DPP ins,
// proven 7x) resized for 6 blocks/CU: single-buffer colT (16KB) + rowT 8KB
// = 24KB LDS; grid 128 x 2 col-halves x 8 = 2048 blocks -> 24 waves/CU
// (was 16). r10-proven 2-barrier/tile pattern: gram -> barrier -> stage(t+1)
// -> scan -> barrier (vmcnt drain). Each half emits a descending top-16
// (fp32 value, uint16 idx) list; k_mlp rank-merges them inline.
__global__ __launch_bounds__(256, 6) void k_knn(const float* __restrict__ fea,
                                                const float* __restrict__ sq,
                                                float* __restrict__ vh,
                                                unsigned short* __restrict__ ih) {
    __shared__ __align__(16) float rowT[64][32];    // 8KB  [c][r]
    __shared__ __align__(16) float colT[64 * 64];   // 16KB [c][j]

    const int b = blockIdx.z;
    const int half = blockIdx.y;
    const int n0 = blockIdx.x * 32;
    const int cbase = half * HALFC;
    const int tid = threadIdx.x;
    const int lane = tid & 63, w = tid >> 6;
    const int g = lane >> 4, p = lane & 15;
    const int rbase = w * 8 + g * 2;                // this lane's 2 rows
    const float* feab = fea + (size_t)b * NCH * NPTS;

    // async stage of colT (64ch x 64 cols) for tile at m0; 4 insts/wave
    auto stage = [&](int m0) {
#pragma unroll
        for (int i = 0; i < 4; ++i) {
            int k = w * 4 + i;                      // chunk: 256 floats
            int c = 4 * k + (lane >> 4);
            int j = (lane & 15) * 4;
            const float* gp = feab + c * NPTS + m0 + j;
            float* lp = &colT[k * 256];             // wave-uniform base
            __builtin_amdgcn_global_load_lds((GLOBAL_AS void*)gp,
                                             (LDS_AS void*)lp, 16, 0, 0);
        }
    };

#pragma unroll
    for (int i = 0; i < 2; ++i) {                   // rowT: 64ch x 32 rows
        int e = i * 1024 + tid * 4;
        int c = e >> 5, r = e & 31;
        *(float4*)&rowT[c][r] = *(const float4*)&feab[c * NPTS + n0 + r];
    }

    float lstv[2];                                  // row rbase+i list,
    int   lsti[2];                                  // lane p = p-th smallest
    float thr[2];                                   // group-uniform list min
#pragma unroll
    for (int i = 0; i < 2; ++i) {
        lstv[i] = -3.0e38f; lsti[i] = 0; thr[i] = -3.0e38f;
    }

    // insert (vv, col) into row-i list; group-uniform call; DPP shift-by-1
    auto ins = [&](int i, float vv, int col) {
        unsigned long long lt = __ballot(lstv[i] < vv);
        int pos = __popc((unsigned)((lt >> (g * 16)) & 0xFFFFu));
        int nv = __builtin_amdgcn_update_dpp(0, __float_as_int(lstv[i]),
                                             0x101, 0xF, 0xF, true);
        int ni = __builtin_amdgcn_update_dpp(0, lsti[i],
                                             0x101, 0xF, 0xF, true);
        if (p <= pos - 2)      { lstv[i] = __int_as_float(nv); lsti[i] = ni; }
        else if (p == pos - 1) { lstv[i] = vv; lsti[i] = col; }
    };

    stage(cbase);                                   // prologue: tile 0
    __syncthreads();                                // vmcnt drain + rowT ready

    for (int t = 0; t < 32; ++t) {
        const int m0 = cbase + t * 64;

        float4 sqc = *(const float4*)&sq[b * NPTS + m0 + p * 4];

        float acc[2][4] = {{0.f,0.f,0.f,0.f},{0.f,0.f,0.f,0.f}};
#pragma unroll 8
        for (int c = 0; c < 64; ++c) {
            float2 rv = *(const float2*)&rowT[c][rbase];
            float4 cv = *(const float4*)&colT[c * 64 + p * 4];
            float cc[4] = {cv.x, cv.y, cv.z, cv.w};
#pragma unroll
            for (int ci = 0; ci < 4; ++ci) {
                acc[0][ci] = fmaf(rv.x, cc[ci], acc[0][ci]);
                acc[1][ci] = fmaf(rv.y, cc[ci], acc[1][ci]);
            }
        }

        __syncthreads();            // all waves done reading colT(t)
        if (t < 31) stage(m0 + 64); // issue t+1 loads; land during scan

        // transform: dist = 2*G - sq[col]
        float sqa[4] = {sqc.x, sqc.y, sqc.z, sqc.w};
#pragma unroll
        for (int i = 0; i < 2; ++i)
#pragma unroll
            for (int j = 0; j < 4; ++j)
                acc[i][j] = fmaf(2.f, acc[i][j], -sqa[j]);

        // ---- scan: 2 rows; lockstep pops across the 4 groups ----
#pragma unroll
        for (int i = 0; i < 2; ++i) {
            float v0 = acc[i][0], v1 = acc[i][1];
            float v2 = acc[i][2], v3 = acc[i][3];
            float vm = fmaxf(fmaxf(v0, v1), fmaxf(v2, v3));
            unsigned long long bal = __ballot(vm > thr[i]);
            unsigned mg = (unsigned)((bal >> (g * 16)) & 0xFFFFull);
            while (__any(mg != 0u)) {
                bool act = (mg != 0u);
                int srcp = act ? (__ffs(mg) - 1) : 0;
                mg &= (mg - 1u);                    // 0 stays 0
                int srcl = (g << 4) | srcp;
                float b0 = __shfl(v0, srcl);        // 4 parallel bcasts
                float b1 = __shfl(v1, srcl);
                float b2 = __shfl(v2, srcl);
                float b3 = __shfl(v3, srcl);
                if (act) {
                    int cb = m0 + srcp * 4;
                    if (b0 > thr[i]) ins(i, b0, cb + 0);
                    if (b1 > thr[i]) ins(i, b1, cb + 1);
                    if (b2 > thr[i]) ins(i, b2, cb + 2);
                    if (b3 > thr[i]) ins(i, b3, cb + 3);
                }
            }
            if (bal) thr[i] = __shfl(lstv[i], 0, 16);
        }
        // barrier: own-wave vmcnt drain completes stage(t+1); all waves'
        // staging writes visible before next gram.
        __syncthreads();
    }

#pragma unroll
    for (int i = 0; i < 2; ++i) {                   // descending half-lists
        int row = rbase + i;
        size_t base = ((size_t)(b * NPTS) + n0 + row) * 32 + half * 16;
        vh[base + (15 - p)] = lstv[i];
        ih[base + (15 - p)] = (unsigned short)lsti[i];
    }
}

// -------------------------------------------- K4: fused MLP + max ----------
// r18: r17 structure (role-swapped GEMMs, f3 in registers, shfl_xor max,
// 5 phases) + INLINE RANK-MERGE of the two half-lists replacing the sidx
// global load: 128 threads, element e of row r gets merged rank =
// own-list position + cross-list count (h0 ties win -> lower index);
// rank<16 -> sidx. Ranks are a permutation of 0..31, so exactly the
// top-16 SET lands in sidx (order within sidx is irrelevant: max over k).
__global__ __launch_bounds__(256) void k_mlp(
    const float* __restrict__ xyz,
    const float* __restrict__ Pt, const float* __restrict__ Qt,
    const float* __restrict__ vh, const unsigned short* __restrict__ ih,
    const float* __restrict__ Wg1, const float* __restrict__ bg1,
    const float* __restrict__ Wg2, const float* __restrict__ bg2,
    const float* __restrict__ Wf2, const float* __restrict__ bf2,
    const float* __restrict__ Wf3, const float* __restrict__ bf3,
    float* __restrict__ out) {
    __shared__ __align__(16) float bufX[64][68];
    __shared__ __align__(16) float bufY[64][68];
    __shared__ __align__(16) float WbufA[64][68];
    __shared__ __align__(16) float WbufB[64][68];
    __shared__ __align__(16) float geoS[10 * 68];
    __shared__ float vbuf[4][32];
    __shared__ unsigned short ibuf[4][32];
    __shared__ float biasA[64], biasB[64];
    __shared__ int sidx[64];

    const int b = blockIdx.y;
    const int n0 = blockIdx.x * 4;
    const int tid = threadIdx.x;
    const int to = tid & 15, tp = tid >> 4;

    // P0: rank-merge the half-lists -> sidx
    if (tid < 128) {
        int r = tid >> 5, e = tid & 31;
        size_t row = (size_t)(b * NPTS) + n0 + r;
        vbuf[r][e] = vh[row * 32 + e];
        ibuf[r][e] = ih[row * 32 + e];
    }
    __syncthreads();
    if (tid < 128) {
        int r = tid >> 5, e = tid & 31;
        float myv = vbuf[r][e];
        int rank;
        if (e < 16) {           // h0 elem: rank = pos + #{h1 strictly above}
            int cnt = 0;
#pragma unroll
            for (int k = 0; k < 16; ++k) cnt += (vbuf[r][16 + k] > myv);
            rank = e + cnt;
        } else {                // h1 elem: rank = pos + #{h0 at-or-above}
            int cnt = 0;
#pragma unroll
            for (int k = 0; k < 16; ++k) cnt += (vbuf[r][k] >= myv);
            rank = (e - 16) + cnt;
        }
        if (rank < 16) sidx[r * 16 + rank] = (int)ibuf[r][e];
    }
    __syncthreads();

    // P1: f1 = relu(P + Q_gather) -> bufX [c][pair]; geo -> geoS; stage W.
    {
        int pair = tid >> 2, q = tid & 3;
        int m = sidx[pair];
        int pt = pair >> 4;
        const float* pB = &Pt[((size_t)b * NPTS + n0 + pt) * 64];
        const float* qB = &Qt[((size_t)b * NPTS + m) * 64];
#pragma unroll
        for (int i = 0; i < 4; ++i) {
            int c0 = q * 16 + i * 4;
            float4 pv = *(const float4*)&pB[c0];
            float4 qv = *(const float4*)&qB[c0];
            bufX[c0 + 0][pair] = fmaxf(pv.x + qv.x, 0.f);
            bufX[c0 + 1][pair] = fmaxf(pv.y + qv.y, 0.f);
            bufX[c0 + 2][pair] = fmaxf(pv.z + qv.z, 0.f);
            bufX[c0 + 3][pair] = fmaxf(pv.w + qv.w, 0.f);
        }
    }
    if (tid < 64) {
        int pair = tid, pt = pair >> 4;
        int m = sidx[pair];
        const float* xb = xyz + (size_t)b * 3 * NPTS;
        float cx = xb[0 * NPTS + n0 + pt], cy = xb[1 * NPTS + n0 + pt], cz = xb[2 * NPTS + n0 + pt];
        float kx = xb[0 * NPTS + m], ky = xb[1 * NPTS + m], kz = xb[2 * NPTS + m];
        float rx = cx - kx, ry = cy - ky, rz = cz - kz;
        float d = sqrtf(rx * rx + ry * ry + rz * rz);
        geoS[0 * 68 + pair] = d;
        geoS[1 * 68 + pair] = cx; geoS[2 * 68 + pair] = cy; geoS[3 * 68 + pair] = cz;
        geoS[4 * 68 + pair] = kx; geoS[5 * 68 + pair] = ky; geoS[6 * 68 + pair] = kz;
        geoS[7 * 68 + pair] = rx; geoS[8 * 68 + pair] = ry; geoS[9 * 68 + pair] = rz;
    }

    auto stageW = [&](const float* W, const float* bv, float (*Wb)[68],
                      float* bias) {
#pragma unroll
        for (int i = 0; i < 4; ++i) {
            int g = tid * 16 + i * 4;
            int o = g >> 6, c = g & 63;
            float4 w = *(const float4*)&W[g];
            Wb[c + 0][o] = w.x; Wb[c + 1][o] = w.y;
            Wb[c + 2][o] = w.z; Wb[c + 3][o] = w.w;
        }
        if (tid < 64) bias[tid] = bv[tid];
    };

    // role-swapped GEMM with LDS output
    auto gemmPh = [&](const float* src, float* dst, int Kdim,
                      const float (*Wb)[68], const float* bias) {
        float acc[4][4] = {{0.f,0.f,0.f,0.f},{0.f,0.f,0.f,0.f},
                           {0.f,0.f,0.f,0.f},{0.f,0.f,0.f,0.f}};
#pragma unroll 2
        for (int c = 0; c < Kdim; ++c) {
            float4 w = *(const float4*)&Wb[c][tp * 4];
            float4 a = *(const float4*)(src + c * 68 + to * 4);
            float wr[4] = {w.x, w.y, w.z, w.w};
            float ar[4] = {a.x, a.y, a.z, a.w};
#pragma unroll
            for (int oi = 0; oi < 4; ++oi)
#pragma unroll
                for (int pj = 0; pj < 4; ++pj)
                    acc[oi][pj] = fmaf(wr[oi], ar[pj], acc[oi][pj]);
        }
#pragma unroll
        for (int oi = 0; oi < 4; ++oi) {
            float bo = bias[tp * 4 + oi];
            float4 o4;
            o4.x = fmaxf(acc[oi][0] + bo, 0.f);
            o4.y = fmaxf(acc[oi][1] + bo, 0.f);
            o4.z = fmaxf(acc[oi][2] + bo, 0.f);
            o4.w = fmaxf(acc[oi][3] + bo, 0.f);
            *(float4*)(dst + (tp * 4 + oi) * 68 + to * 4) = o4;
        }
    };

    stageW(Wf2, bf2, WbufA, biasA);
    stageW(Wf3, bf3, WbufB, biasB);
    __syncthreads();                                   // end P1

    gemmPh(&bufX[0][0], &bufY[0][0], 64, WbufA, biasA);   // P2: f2
    __syncthreads();                                   // end P2

    // P3: f3 -> REGISTERS (reads bufY, WbufB) + stage Wg1 -> A
    float f3r[4][4];
    {
        float acc[4][4] = {{0.f,0.f,0.f,0.f},{0.f,0.f,0.f,0.f},
                           {0.f,0.f,0.f,0.f},{0.f,0.f,0.f,0.f}};
#pragma unroll 2
        for (int c = 0; c < 64; ++c) {
            float4 w = *(const float4*)&WbufB[c][tp * 4];
            float4 a = *(const float4*)&bufY[c][to * 4];
            float wr[4] = {w.x, w.y, w.z, w.w};
            float ar[4] = {a.x, a.y, a.z, a.w};
#pragma unroll
            for (int oi = 0; oi < 4; ++oi)
#pragma unroll
                for (int pj = 0; pj < 4; ++pj)
                    acc[oi][pj] = fmaf(wr[oi], ar[pj], acc[oi][pj]);
        }
#pragma unroll
        for (int oi = 0; oi < 4; ++oi) {
            float bo = biasB[tp * 4 + oi];
            f3r[oi][0] = fmaxf(acc[oi][0] + bo, 0.f);
            f3r[oi][1] = fmaxf(acc[oi][1] + bo, 0.f);
            f3r[oi][2] = fmaxf(acc[oi][2] + bo, 0.f);
            f3r[oi][3] = fmaxf(acc[oi][3] + bo, 0.f);
        }
    }
    {   // stage Wg1 -> A (A free since end of P2); Wg1 is 64x10
        for (int e = tid; e < 640; e += 256) {
            int o = e / 10, c = e - o * 10;
            WbufA[c][o] = Wg1[e];
        }
        if (tid < 64) biasA[tid] = bg1[tid];
    }
    __syncthreads();                                   // end P3

    // P4: g1: geoS -> bufY (bufY free after f3) + stage Wg2 -> B
    gemmPh(geoS, &bufY[0][0], 10, WbufA, biasA);
    stageW(Wg2, bg2, WbufB, biasB);
    __syncthreads();                                   // end P4

    // P5: g2 (bufY, WbufB) + fused *f3r + shfl_xor max + store
    {
        float acc[4][4] = {{0.f,0.f,0.f,0.f},{0.f,0.f,0.f,0.f},
                           {0.f,0.f,0.f,0.f},{0.f,0.f,0.f,0.f}};
#pragma unroll 2
        for (int c = 0; c < 64; ++c) {
            float4 w = *(const float4*)&WbufB[c][tp * 4];
            float4 a = *(const float4*)&bufY[c][to * 4];
            float wr[4] = {w.x, w.y, w.z, w.w};
            float ar[4] = {a.x, a.y, a.z, a.w};
#pragma unroll
            for (int oi = 0; oi < 4; ++oi)
#pragma unroll
                for (int pj = 0; pj < 4; ++pj)
                    acc[oi][pj] = fmaf(wr[oi], ar[pj], acc[oi][pj]);
        }
        float mx[4];
#pragma unroll
        for (int oi = 0; oi < 4; ++oi) {
            float bo = biasB[tp * 4 + oi];
            float m0_ = fmaxf(acc[oi][0] + bo, 0.f) * f3r[oi][0];
            float m1_ = fmaxf(acc[oi][1] + bo, 0.f) * f3r[oi][1];
            float m2_ = fmaxf(acc[oi][2] + bo, 0.f) * f3r[oi][2];
            float m3_ = fmaxf(acc[oi][3] + bo, 0.f) * f3r[oi][3];
            mx[oi] = fmaxf(fmaxf(m0_, m1_), fmaxf(m2_, m3_));
        }
#pragma unroll
        for (int oi = 0; oi < 4; ++oi) {
            mx[oi] = fmaxf(mx[oi], __shfl_xor(mx[oi], 1));
            mx[oi] = fmaxf(mx[oi], __shfl_xor(mx[oi], 2));
        }
        if ((to & 3) == 0) {
            int pt = to >> 2;
#pragma unroll
            for (int oi = 0; oi < 4; ++oi) {
                int o = tp * 4 + oi;
                out[((size_t)b * 64 + o) * NPTS + n0 + pt] = mx[oi];
            }
        }
    }
}

// ---------------------------------------------------------------------------
extern "C" void kernel_launch(void* const* d_in, const int* in_sizes, int n_in,
                              void* d_out, int out_size, void* d_ws, size_t ws_size,
                              hipStream_t stream) {
    const float* xyz = (const float*)d_in[0];
    const float* fea = (const float*)d_in[1];
    const float* Wg1 = (const float*)d_in[2];
    const float* bg1 = (const float*)d_in[3];
    const float* Wg2 = (const float*)d_in[4];
    const float* bg2 = (const float*)d_in[5];
    const float* Wf1 = (const float*)d_in[6];
    const float* bf1 = (const float*)d_in[7];
    const float* Wf2 = (const float*)d_in[8];
    const float* bf2 = (const float*)d_in[9];
    const float* Wf3 = (const float*)d_in[10];
    const float* bf3 = (const float*)d_in[11];
    float* out = (float*)d_out;
    float* ws = (float*)d_ws;

    float* sq = ws + WS_SQ;
    float* Pt = ws + WS_PT;
    float* Qt = ws + WS_QT;
    float* vh = ws + WS_VH;
    unsigned short* ih = (unsigned short*)(ws + WS_IH);

    k_pq  <<<dim3(64, 8),     dim3(256), 0, stream>>>(fea, Wf1, bf1, Pt, Qt, sq);
    k_knn <<<dim3(128, 2, 8), dim3(256), 0, stream>>>(fea, sq, vh, ih);
    k_mlp <<<dim3(1024, 8),   dim3(256), 0, stream>>>(xyz, Pt, Qt, vh, ih,
                                                      Wg1, bg1, Wg2, bg2,
                                                      Wf2, bf2, Wf3, bf3, out);
}

// Round 19
// 621.732 us; speedup vs baseline: 1.1043x; 1.1043x over previous
//
#include <hip/hip_runtime.h>
#include <math.h>

#define NB 8
#define NPTS 4096
#define NCH 64
#define NOUT 64
#define KNN 16

#define GLOBAL_AS const __attribute__((address_space(1)))
#define LDS_AS __attribute__((address_space(3)))

// ws layout in floats:
#define WS_SQ  0
#define WS_PT  (NB*NPTS)                       // 32768
#define WS_QT  (WS_PT + NB*NPTS*64)            // + 2097152
#define WS_IDX (WS_QT + NB*NPTS*64)            // int32 region, NB*NPTS*16 ints

// ------------------------------------------------------- K2: fused KNN ------
// byte-exact r12 (fastest, measured 7x at 442us). 32-row panels, full-range
// top-16 list, dbuf colT, 1 barrier/tile, 4 blocks/CU, ballot+DPP ins.
__global__ __launch_bounds__(256, 4) void k_knn(const float* __restrict__ fea,
                                                const float* __restrict__ sq,
                                                int* __restrict__ idxout) {
    __shared__ __align__(16) float rowT[64][32];     // 8KB  [c][r]
    __shared__ __align__(16) float colT[2][64 * 64]; // 32KB [c][j] dbuf

    const int b = blockIdx.y;
    const int n0 = blockIdx.x * 32;
    const int tid = threadIdx.x;
    const int lane = tid & 63, w = tid >> 6;
    const int g = lane >> 4, p = lane & 15;
    const int rbase = w * 8 + g * 2;                // this lane's 2 rows
    const float* feab = fea + (size_t)b * NCH * NPTS;

    // async stage of colT[buf] (64ch x 64 cols) for tile at m0; 4 insts/wave
    auto stage = [&](int buf, int m0) {
#pragma unroll
        for (int i = 0; i < 4; ++i) {
            int k = w * 4 + i;                      // chunk: 256 floats
            int c = 4 * k + (lane >> 4);
            int j = (lane & 15) * 4;
            const float* gp = feab + c * NPTS + m0 + j;
            float* lp = &colT[buf][k * 256];        // wave-uniform base
            __builtin_amdgcn_global_load_lds((GLOBAL_AS void*)gp,
                                             (LDS_AS void*)lp, 16, 0, 0);
        }
    };

#pragma unroll
    for (int i = 0; i < 2; ++i) {                   // rowT: 64ch x 32 rows
        int e = i * 1024 + tid * 4;
        int c = e >> 5, r = e & 31;
        *(float4*)&rowT[c][r] = *(const float4*)&feab[c * NPTS + n0 + r];
    }

    float lstv[2];                                  // row rbase+i list,
    int   lsti[2];                                  // lane p = p-th smallest
    float thr[2];                                   // group-uniform list min
#pragma unroll
    for (int i = 0; i < 2; ++i) {
        lstv[i] = -3.0e38f; lsti[i] = 0; thr[i] = -3.0e38f;
    }

    // insert (vv, col) into row-i list; group-uniform call; DPP shift-by-1
    auto ins = [&](int i, float vv, int col) {
        unsigned long long lt = __ballot(lstv[i] < vv);
        int pos = __popc((unsigned)((lt >> (g * 16)) & 0xFFFFu));
        int nv = __builtin_amdgcn_update_dpp(0, __float_as_int(lstv[i]),
                                             0x101, 0xF, 0xF, true);
        int ni = __builtin_amdgcn_update_dpp(0, lsti[i],
                                             0x101, 0xF, 0xF, true);
        if (p <= pos - 2)      { lstv[i] = __int_as_float(nv); lsti[i] = ni; }
        else if (p == pos - 1) { lstv[i] = vv; lsti[i] = col; }
    };

    stage(0, 0);                                    // prologue: tile 0
    __syncthreads();                                // vmcnt drain + rowT ready

    for (int t = 0; t < 64; ++t) {
        const int m0 = t * 64;
        const int cur = t & 1;
        if (t < 63) stage(cur ^ 1, m0 + 64);        // prefetch next tile NOW

        float4 sqc = *(const float4*)&sq[b * NPTS + m0 + p * 4];

        float acc[2][4] = {{0.f,0.f,0.f,0.f},{0.f,0.f,0.f,0.f}};
#pragma unroll 8
        for (int c = 0; c < 64; ++c) {
            float2 rv = *(const float2*)&rowT[c][rbase];
            float4 cv = *(const float4*)&colT[cur][c * 64 + p * 4];
            float cc[4] = {cv.x, cv.y, cv.z, cv.w};
#pragma unroll
            for (int ci = 0; ci < 4; ++ci) {
                acc[0][ci] = fmaf(rv.x, cc[ci], acc[0][ci]);
                acc[1][ci] = fmaf(rv.y, cc[ci], acc[1][ci]);
            }
        }

        // transform: dist = 2*G - sq[col]
        float sqa[4] = {sqc.x, sqc.y, sqc.z, sqc.w};
#pragma unroll
        for (int i = 0; i < 2; ++i)
#pragma unroll
            for (int j = 0; j < 4; ++j)
                acc[i][j] = fmaf(2.f, acc[i][j], -sqa[j]);

        // ---- scan: 2 rows; lockstep pops across the 4 groups ----
#pragma unroll
        for (int i = 0; i < 2; ++i) {
            float v0 = acc[i][0], v1 = acc[i][1];
            float v2 = acc[i][2], v3 = acc[i][3];
            float vm = fmaxf(fmaxf(v0, v1), fmaxf(v2, v3));
            unsigned long long bal = __ballot(vm > thr[i]);
            unsigned mg = (unsigned)((bal >> (g * 16)) & 0xFFFFull);
            while (__any(mg != 0u)) {
                bool act = (mg != 0u);
                int srcp = act ? (__ffs(mg) - 1) : 0;
                mg &= (mg - 1u);                    // 0 stays 0
                int srcl = (g << 4) | srcp;
                float b0 = __shfl(v0, srcl);        // 4 parallel bcasts
                float b1 = __shfl(v1, srcl);
                float b2 = __shfl(v2, srcl);
                float b3 = __shfl(v3, srcl);
                if (act) {
                    int cb = m0 + srcp * 4;
                    if (b0 > thr[i]) ins(i, b0, cb + 0);
                    if (b1 > thr[i]) ins(i, b1, cb + 1);
                    if (b2 > thr[i]) ins(i, b2, cb + 2);
                    if (b3 > thr[i]) ins(i, b3, cb + 3);
                }
            }
            if (bal) thr[i] = __shfl(lstv[i], 0, 16);
        }
        // single barrier: own-wave vmcnt drain completes the prefetch of
        // colT[cur^1]; sync makes all waves' staging writes visible.
        __syncthreads();
    }

#pragma unroll
    for (int i = 0; i < 2; ++i) {                   // descending output
        int row = rbase + i;
        idxout[((size_t)(b * NPTS) + n0 + row) * KNN + (15 - p)] = lsti[i];
    }
}

// ----------------------------- K3: P/Q precompute (+ fused sq) -------------
__global__ __launch_bounds__(256) void k_pq(const float* __restrict__ fea,
                                            const float* __restrict__ Wf1,
                                            const float* __restrict__ bf1,
                                            float* __restrict__ Pt,
                                            float* __restrict__ Qt,
                                            float* __restrict__ sq) {
    __shared__ __align__(16) float feaT[64][64];    // [c][n]
    __shared__ __align__(16) float WT[64][132];     // [c][o'], o' in 0..127
    __shared__ float sb[64];

    const int b = blockIdx.y;
    const int n0 = blockIdx.x * 64;
    const int tid = threadIdx.x;
    const int to = tid & 15, tn = tid >> 4;
    const float* feab = fea + (size_t)b * NCH * NPTS;

#pragma unroll
    for (int i = 0; i < 4; ++i) {
        int e = i * 1024 + tid * 4;
        int c = e >> 6, nn = e & 63;
        *(float4*)&feaT[c][nn] = *(const float4*)&feab[c * NPTS + n0 + nn];
    }
#pragma unroll
    for (int i = 0; i < 8; ++i) {
        int g = tid * 32 + i * 4;
        int op = g >> 6, c = g & 63;
        const float* src = (op < 64) ? &Wf1[op * 128 + c]
                                     : &Wf1[(op - 64) * 128 + 64 + c];
        float4 w = *(const float4*)src;
        WT[c + 0][op] = w.x; WT[c + 1][op] = w.y;
        WT[c + 2][op] = w.z; WT[c + 3][op] = w.w;
    }
    if (tid < 64) sb[tid] = bf1[tid];
    __syncthreads();

    if (tid < 64) {                                 // fused k_sq
        float s = 0.f;
#pragma unroll
        for (int c = 0; c < 64; ++c) {
            float v = feaT[c][tid];
            s = fmaf(v, v, s);
        }
        sq[b * NPTS + n0 + tid] = s;
    }

    float acc[4][8];
#pragma unroll
    for (int ni = 0; ni < 4; ++ni)
#pragma unroll
        for (int oj = 0; oj < 8; ++oj) acc[ni][oj] = 0.f;

#pragma unroll 4
    for (int c = 0; c < 64; ++c) {
        float4 a  = *(const float4*)&feaT[c][tn * 4];
        float4 w0 = *(const float4*)&WT[c][to * 8];
        float4 w1 = *(const float4*)&WT[c][to * 8 + 4];
        float av[4] = {a.x, a.y, a.z, a.w};
        float wv[8] = {w0.x, w0.y, w0.z, w0.w, w1.x, w1.y, w1.z, w1.w};
#pragma unroll
        for (int ni = 0; ni < 4; ++ni)
#pragma unroll
            for (int oj = 0; oj < 8; ++oj)
                acc[ni][oj] = fmaf(av[ni], wv[oj], acc[ni][oj]);
    }

    const int opb = to * 8;
#pragma unroll
    for (int ni = 0; ni < 4; ++ni) {
        int n = n0 + tn * 4 + ni;
        size_t base = ((size_t)b * NPTS + n) * 64;
        if (opb < 64) {     // P half: add bias
            float4 o0, o1;
            o0.x = acc[ni][0] + sb[opb + 0]; o0.y = acc[ni][1] + sb[opb + 1];
            o0.z = acc[ni][2] + sb[opb + 2]; o0.w = acc[ni][3] + sb[opb + 3];
            o1.x = acc[ni][4] + sb[opb + 4]; o1.y = acc[ni][5] + sb[opb + 5];
            o1.z = acc[ni][6] + sb[opb + 6]; o1.w = acc[ni][7] + sb[opb + 7];
            *(float4*)&Pt[base + opb]     = o0;
            *(float4*)&Pt[base + opb + 4] = o1;
        } else {            // Q half: no bias
            float4 o0, o1;
            o0.x = acc[ni][0]; o0.y = acc[ni][1]; o0.z = acc[ni][2]; o0.w = acc[ni][3];
            o1.x = acc[ni][4]; o1.y = acc[ni][5]; o1.z = acc[ni][6]; o1.w = acc[ni][7];
            *(float4*)&Qt[base + opb - 64]     = o0;
            *(float4*)&Qt[base + opb - 64 + 4] = o1;
        }
    }
}

// -------------------------------------------- K4: fused MLP + max ----------
// r17 structure: role-swapped GEMMs (rows o = tp*4+oi, pair cols to*4+pj),
// f3 kept in registers (no bufX round-trip), shfl_xor final max, dual
// weight buffers; phases P1..P5, 5 barriers total.
__global__ __launch_bounds__(256) void k_mlp(
    const float* __restrict__ xyz,
    const float* __restrict__ Pt, const float* __restrict__ Qt,
    const int* __restrict__ knnidx,
    const float* __restrict__ Wg1, const float* __restrict__ bg1,
    const float* __restrict__ Wg2, const float* __restrict__ bg2,
    const float* __restrict__ Wf2, const float* __restrict__ bf2,
    const float* __restrict__ Wf3, const float* __restrict__ bf3,
    float* __restrict__ out) {
    __shared__ __align__(16) float bufX[64][68];
    __shared__ __align__(16) float bufY[64][68];
    __shared__ __align__(16) float WbufA[64][68];
    __shared__ __align__(16) float WbufB[64][68];
    __shared__ __align__(16) float geoS[10 * 68];
    __shared__ float biasA[64], biasB[64];
    __shared__ int sidx[64];

    const int b = blockIdx.y;
    const int n0 = blockIdx.x * 4;
    const int tid = threadIdx.x;
    const int to = tid & 15, tp = tid >> 4;

    if (tid < 64)
        sidx[tid] = knnidx[((size_t)(b * NPTS + n0)) * KNN + tid];
    __syncthreads();

    // P1: f1 = relu(P + Q_gather) -> bufX [c][pair]; geo -> geoS; stage W.
    {
        int pair = tid >> 2, q = tid & 3;
        int m = sidx[pair];
        int pt = pair >> 4;
        const float* pB = &Pt[((size_t)b * NPTS + n0 + pt) * 64];
        const float* qB = &Qt[((size_t)b * NPTS + m) * 64];
#pragma unroll
        for (int i = 0; i < 4; ++i) {
            int c0 = q * 16 + i * 4;
            float4 pv = *(const float4*)&pB[c0];
            float4 qv = *(const float4*)&qB[c0];
            bufX[c0 + 0][pair] = fmaxf(pv.x + qv.x, 0.f);
            bufX[c0 + 1][pair] = fmaxf(pv.y + qv.y, 0.f);
            bufX[c0 + 2][pair] = fmaxf(pv.z + qv.z, 0.f);
            bufX[c0 + 3][pair] = fmaxf(pv.w + qv.w, 0.f);
        }
    }
    if (tid < 64) {
        int pair = tid, pt = pair >> 4;
        int m = sidx[pair];
        const float* xb = xyz + (size_t)b * 3 * NPTS;
        float cx = xb[0 * NPTS + n0 + pt], cy = xb[1 * NPTS + n0 + pt], cz = xb[2 * NPTS + n0 + pt];
        float kx = xb[0 * NPTS + m], ky = xb[1 * NPTS + m], kz = xb[2 * NPTS + m];
        float rx = cx - kx, ry = cy - ky, rz = cz - kz;
        float d = sqrtf(rx * rx + ry * ry + rz * rz);
        geoS[0 * 68 + pair] = d;
        geoS[1 * 68 + pair] = cx; geoS[2 * 68 + pair] = cy; geoS[3 * 68 + pair] = cz;
        geoS[4 * 68 + pair] = kx; geoS[5 * 68 + pair] = ky; geoS[6 * 68 + pair] = kz;
        geoS[7 * 68 + pair] = rx; geoS[8 * 68 + pair] = ry; geoS[9 * 68 + pair] = rz;
    }

    auto stageW = [&](const float* W, const float* bv, float (*Wb)[68],
                      float* bias) {
#pragma unroll
        for (int i = 0; i < 4; ++i) {
            int g = tid * 16 + i * 4;
            int o = g >> 6, c = g & 63;
            float4 w = *(const float4*)&W[g];
            Wb[c + 0][o] = w.x; Wb[c + 1][o] = w.y;
            Wb[c + 2][o] = w.z; Wb[c + 3][o] = w.w;
        }
        if (tid < 64) bias[tid] = bv[tid];
    };

    // role-swapped GEMM with LDS output
    auto gemmPh = [&](const float* src, float* dst, int Kdim,
                      const float (*Wb)[68], const float* bias) {
        float acc[4][4] = {{0.f,0.f,0.f,0.f},{0.f,0.f,0.f,0.f},
                           {0.f,0.f,0.f,0.f},{0.f,0.f,0.f,0.f}};
#pragma unroll 2
        for (int c = 0; c < Kdim; ++c) {
            float4 w = *(const float4*)&Wb[c][tp * 4];
            float4 a = *(const float4*)(src + c * 68 + to * 4);
            float wr[4] = {w.x, w.y, w.z, w.w};
            float ar[4] = {a.x, a.y, a.z, a.w};
#pragma unroll
            for (int oi = 0; oi < 4; ++oi)
#pragma unroll
                for (int pj = 0; pj < 4; ++pj)
                    acc[oi][pj] = fmaf(wr[oi], ar[pj], acc[oi][pj]);
        }
#pragma unroll
        for (int oi = 0; oi < 4; ++oi) {
            float bo = bias[tp * 4 + oi];
            float4 o4;
            o4.x = fmaxf(acc[oi][0] + bo, 0.f);
            o4.y = fmaxf(acc[oi][1] + bo, 0.f);
            o4.z = fmaxf(acc[oi][2] + bo, 0.f);
            o4.w = fmaxf(acc[oi][3] + bo, 0.f);
            *(float4*)(dst + (tp * 4 + oi) * 68 + to * 4) = o4;
        }
    };

    stageW(Wf2, bf2, WbufA, biasA);
    stageW(Wf3, bf3, WbufB, biasB);
    __syncthreads();                                   // end P1

    gemmPh(&bufX[0][0], &bufY[0][0], 64, WbufA, biasA);   // P2: f2
    __syncthreads();                                   // end P2

    // P3: f3 -> REGISTERS (reads bufY, WbufB) + stage Wg1 -> A
    float f3r[4][4];
    {
        float acc[4][4] = {{0.f,0.f,0.f,0.f},{0.f,0.f,0.f,0.f},
                           {0.f,0.f,0.f,0.f},{0.f,0.f,0.f,0.f}};
#pragma unroll 2
        for (int c = 0; c < 64; ++c) {
            float4 w = *(const float4*)&WbufB[c][tp * 4];
            float4 a = *(const float4*)&bufY[c][to * 4];
            float wr[4] = {w.x, w.y, w.z, w.w};
            float ar[4] = {a.x, a.y, a.z, a.w};
#pragma unroll
            for (int oi = 0; oi < 4; ++oi)
#pragma unroll
                for (int pj = 0; pj < 4; ++pj)
                    acc[oi][pj] = fmaf(wr[oi], ar[pj], acc[oi][pj]);
        }
#pragma unroll
        for (int oi = 0; oi < 4; ++oi) {
            float bo = biasB[tp * 4 + oi];
            f3r[oi][0] = fmaxf(acc[oi][0] + bo, 0.f);
            f3r[oi][1] = fmaxf(acc[oi][1] + bo, 0.f);
            f3r[oi][2] = fmaxf(acc[oi][2] + bo, 0.f);
            f3r[oi][3] = fmaxf(acc[oi][3] + bo, 0.f);
        }
    }
    {   // stage Wg1 -> A (A free since end of P2); Wg1 is 64x10
        for (int e = tid; e < 640; e += 256) {
            int o = e / 10, c = e - o * 10;
            WbufA[c][o] = Wg1[e];
        }
        if (tid < 64) biasA[tid] = bg1[tid];
    }
    __syncthreads();                                   // end P3

    // P4: g1: geoS -> bufY (bufY free after f3) + stage Wg2 -> B
    gemmPh(geoS, &bufY[0][0], 10, WbufA, biasA);
    stageW(Wg2, bg2, WbufB, biasB);
    __syncthreads();                                   // end P4

    // P5: g2 (bufY, WbufB) + fused *f3r + shfl_xor max + store
    {
        float acc[4][4] = {{0.f,0.f,0.f,0.f},{0.f,0.f,0.f,0.f},
                           {0.f,0.f,0.f,0.f},{0.f,0.f,0.f,0.f}};
#pragma unroll 2
        for (int c = 0; c < 64; ++c) {
            float4 w = *(const float4*)&WbufB[c][tp * 4];
            float4 a = *(const float4*)&bufY[c][to * 4];
            float wr[4] = {w.x, w.y, w.z, w.w};
            float ar[4] = {a.x, a.y, a.z, a.w};
#pragma unroll
            for (int oi = 0; oi < 4; ++oi)
#pragma unroll
                for (int pj = 0; pj < 4; ++pj)
                    acc[oi][pj] = fmaf(wr[oi], ar[pj], acc[oi][pj]);
        }
        float mx[4];
#pragma unroll
        for (int oi = 0; oi < 4; ++oi) {
            float bo = biasB[tp * 4 + oi];
            float m0_ = fmaxf(acc[oi][0] + bo, 0.f) * f3r[oi][0];
            float m1_ = fmaxf(acc[oi][1] + bo, 0.f) * f3r[oi][1];
            float m2_ = fmaxf(acc[oi][2] + bo, 0.f) * f3r[oi][2];
            float m3_ = fmaxf(acc[oi][3] + bo, 0.f) * f3r[oi][3];
            mx[oi] = fmaxf(fmaxf(m0_, m1_), fmaxf(m2_, m3_));
        }
#pragma unroll
        for (int oi = 0; oi < 4; ++oi) {
            mx[oi] = fmaxf(mx[oi], __shfl_xor(mx[oi], 1));
            mx[oi] = fmaxf(mx[oi], __shfl_xor(mx[oi], 2));
        }
        if ((to & 3) == 0) {
            int pt = to >> 2;
#pragma unroll
            for (int oi = 0; oi < 4; ++oi) {
                int o = tp * 4 + oi;
                out[((size_t)b * 64 + o) * NPTS + n0 + pt] = mx[oi];
            }
        }
    }
}

// ---------------------------------------------------------------------------
extern "C" void kernel_launch(void* const* d_in, const int* in_sizes, int n_in,
                              void* d_out, int out_size, void* d_ws, size_t ws_size,
                              hipStream_t stream) {
    const float* xyz = (const float*)d_in[0];
    const float* fea = (const float*)d_in[1];
    const float* Wg1 = (const float*)d_in[2];
    const float* bg1 = (const float*)d_in[3];
    const float* Wg2 = (const float*)d_in[4];
    const float* bg2 = (const float*)d_in[5];
    const float* Wf1 = (const float*)d_in[6];
    const float* bf1 = (const float*)d_in[7];
    const float* Wf2 = (const float*)d_in[8];
    const float* bf2 = (const float*)d_in[9];
    const float* Wf3 = (const float*)d_in[10];
    const float* bf3 = (const float*)d_in[11];
    float* out = (float*)d_out;
    float* ws = (float*)d_ws;

    float* sq = ws + WS_SQ;
    float* Pt = ws + WS_PT;
    float* Qt = ws + WS_QT;
    int* idxw = (int*)(ws + WS_IDX);

    k_pq  <<<dim3(64, 8),    dim3(256), 0, stream>>>(fea, Wf1, bf1, Pt, Qt, sq);
    k_knn <<<dim3(128, 8),   dim3(256), 0, stream>>>(fea, sq, idxw);
    k_mlp <<<dim3(1024, 8),  dim3(256), 0, stream>>>(xyz, Pt, Qt, idxw,
                                                     Wg1, bg1, Wg2, bg2,
                                                     Wf2, bf2, Wf3, bf3, out);
}